// Round 9
// baseline (68.162 us; speedup 1.0000x reference)
//
#include <hip/hip_runtime.h>

#define BB 512
#define TT 30
#define HH 41
#define WFW 40
#define NSEC 9
#define SECLEN 4
#define NF 50
#define KH 6
#define THRESH 23.0f
#define NBT (BB*TT)                 // 15360 (b,t) rows
#define WIN_CNT (NSEC*BB)           // 4608 winners precede pots in d_out
#define NT_HALF 15                  // t-rows per block (half a batch)
#define ROWF (HH*WFW)               // 1640 floats per (b,t) row
#define SLAB_B 3360                 // bytes/slab: 1680 bf16; 3360%128==32 -> uniform banks
#define XBYTES (NT_HALF*SLAB_B)     // 50400
#define NFRAG (NSEC*2*15)           // 270 B-fragments (i, Nt, ks)
#define WSW_BYTES (NFRAG*64*16)     // 276480
#define MASK_BYTES (NSEC*BB*2*64*4) // 2359296: u32 half-masks [i][b][h][f64]

typedef __attribute__((ext_vector_type(8)))  short short8;   // 8 bf16 = 4 VGPR
typedef __attribute__((ext_vector_type(16))) float f32x16;   // 32x32 acc

// ---------------------------------------------------------------------------
// Pre-kernel: W fp32 -> bf16 B-fragments for mfma_f32_32x32x16_bf16.
// Fragment (i,Nt,ks): lane l holds B[k][f], f = Nt*32+(l&31), k = ks*16 +
// (l>>5)*8 + j. Zero for f>=50. K=240 exact (no pad).
// ---------------------------------------------------------------------------
__global__ __launch_bounds__(256) void wconv_kernel(const float* __restrict__ W,
                                                    unsigned char* __restrict__ wsw)
{
    int gid  = blockIdx.x * 256 + threadIdx.x;
    int frag = gid >> 6, l = gid & 63;
    if (frag >= NFRAG) return;
    int i   = frag / 30, rem = frag - i * 30;
    int Nt  = rem / 15,  ks  = rem - Nt * 15;
    int f   = Nt * 32 + (l & 31);
    int kb  = ks * 16 + (l >> 5) * 8;
    unsigned d0 = 0, d1 = 0, d2 = 0, d3 = 0;
    if (f < NF) {
        const float* src = W + (size_t)(i * NF + f) * (KH * WFW) + kb;
        float4 v0 = ((const float4*)src)[0];
        float4 v1 = ((const float4*)src)[1];
        float vv[8] = {v0.x, v0.y, v0.z, v0.w, v1.x, v1.y, v1.z, v1.w};
        unsigned r[8];
        #pragma unroll
        for (int j = 0; j < 8; ++j) {
            unsigned a = __float_as_uint(vv[j]);
            r[j] = (a + 0x7FFFu + ((a >> 16) & 1u)) >> 16;   // RNE to bf16
        }
        d0 = r[0] | (r[1] << 16); d1 = r[2] | (r[3] << 16);
        d2 = r[4] | (r[5] << 16); d3 = r[6] | (r[7] << 16);
    }
    ((uint4*)wsw)[(size_t)frag * 64 + l] = make_uint4(d0, d1, d2, d3);
}

// ---------------------------------------------------------------------------
// Main kernel: block = (batch b, half h) = 15 t-rows, ALL 9 sections.
// 32x32x16 MFMA: wave (Mt,Nt) owns one 32x32 tile; 15 K-steps/section.
// A-frag: row=l&31 -> m=Mt*32+(l&31) (clamp 59), k=8*(l>>5)+j. Halves A-LDS
// traffic per FLOP vs 16x16x32. 1-deep A/B register prefetch pipeline.
// C/D: row=(reg&3)+8*(reg>>2)+4*(l>>5) -> per reg-quad one float4 store at
// (t_loc=Mt*8+2rq+(l>>5), s=reg&3). Winners fused via ballot masks.
// ---------------------------------------------------------------------------
template<bool WRITE_MASK>
__global__ __launch_bounds__(256, 3) void pots_mfma(const float* __restrict__ x,
                                                    const unsigned char* __restrict__ wsw,
                                                    float* __restrict__ out,
                                                    unsigned* __restrict__ msk)
{
    __shared__ alignas(16) unsigned char xs[XBYTES];            // 50400 B
    __shared__ unsigned long long wsc[NSEC * 4 * 4];            // 1152 B
    const int tid = threadIdx.x;
    const int blk = blockIdx.x;                 // b*2 + h
    const int b   = blk >> 1, h = blk & 1;
    const int bt0 = b * TT + h * NT_HALF;

    // ---- stage 15 full x rows (1640 floats each) -> bf16 slabs, coalesced --
    const float* xg = x + (size_t)bt0 * ROWF;
    #pragma unroll
    for (int it = 0; it < 25; ++it) {
        int idx = tid + it * 256;               // float4 index, 15*410 = 6150
        if (idx < NT_HALF * 410) {
            int r = idx / 410, pos = idx - r * 410;
            const float4 v = *(const float4*)(xg + (size_t)r * ROWF + pos * 4);
            unsigned u0 = __float_as_uint(v.x), u1 = __float_as_uint(v.y);
            unsigned u2 = __float_as_uint(v.z), u3 = __float_as_uint(v.w);
            uint2 p;                            // x in {0,1}: truncation exact
            p.x = (u0 >> 16) | (u1 & 0xFFFF0000u);
            p.y = (u2 >> 16) | (u3 & 0xFFFF0000u);
            *(uint2*)(xs + r * SLAB_B + pos * 8) = p;
        }
    }
    __syncthreads();

    const int l   = tid & 63, wid = tid >> 6;
    const int Mt  = wid & 1, Nt = wid >> 1;     // wave = (M-tile, N-tile)
    const int qp  = l >> 5;                     // k-half (A/B), t-parity (D)
    const int c31 = l & 31;
    const int ff  = Nt * 32 + c31;              // global f (D col)

    int m = Mt * 32 + c31; if (m > 59) m = 59;  // clamped rows are discarded
    const unsigned abase = (unsigned)(m >> 2) * SLAB_B + (unsigned)(m & 3) * 80
                         + (unsigned)qp * 16;
    const unsigned char* wbN = wsw + (size_t)(Nt * 15) * 1024 + (size_t)l * 16;
    float4* const pout = (float4*)(out + WIN_CNT);

    #pragma unroll
    for (int i = 0; i < NSEC; ++i) {
        const unsigned char* wbi = wbN + (size_t)i * (30 * 1024);
        const unsigned ib = (unsigned)i * 320;  // slab elem 160*i -> +320 B

        f32x16 acc = {0.f,0.f,0.f,0.f,0.f,0.f,0.f,0.f,
                      0.f,0.f,0.f,0.f,0.f,0.f,0.f,0.f};
        short8 bcur = *(const short8*)(wbi);
        short8 acur = *(const short8*)(xs + abase + ib);
        #pragma unroll
        for (int ks = 0; ks < 15; ++ks) {
            short8 bn = (ks < 14) ? *(const short8*)(wbi + (ks + 1) * 1024) : bcur;
            short8 an = (ks < 14) ? *(const short8*)(xs + abase + ib + (ks + 1) * 32) : acur;
            acc = __builtin_amdgcn_mfma_f32_32x32x16_bf16(acur, bcur, acc, 0, 0, 0);
            bcur = bn; acur = an;
        }

        #pragma unroll
        for (int rq = 0; rq < 4; ++rq) {
            const int t_loc = Mt * 8 + rq * 2 + qp;
            float m2 = fmaxf(fmaxf(acc[4*rq+0], acc[4*rq+1]),
                             fmaxf(acc[4*rq+2], acc[4*rq+3]));
            unsigned long long bal = __ballot(m2 >= THRESH);   // all 64 lanes
            if (WRITE_MASK && l == 0) wsc[(i * 4 + wid) * 4 + rq] = bal;
            if (t_loc < NT_HALF && ff < NF) {
                size_t o = ((size_t)i * NBT + bt0 + t_loc) * NF + ff;
                pout[o] = make_float4(acc[4*rq+0], acc[4*rq+1],
                                      acc[4*rq+2], acc[4*rq+3]);
            }
        }
    }

    if (WRITE_MASK) {
        __syncthreads();
        // assemble 15-bit t-mask per (i, f); bit l of wsc[i][2Nt+Mt][rq]:
        // f = Nt*32+(l&31), t_loc = Mt*8+2rq+(l>>5)
        #pragma unroll
        for (int it = 0; it < 3; ++it) {
            int idx = tid + it * 256;           // 9*64 = 576 entries
            if (idx < NSEC * 64) {
                int i  = idx >> 6, f = idx & 63;
                int ng = f >> 5,  fl = f & 31;
                unsigned mres = 0;
                #pragma unroll
                for (int Mtt = 0; Mtt < 2; ++Mtt) {
                    #pragma unroll
                    for (int rq = 0; rq < 4; ++rq) {
                        unsigned long long w = wsc[(i * 4 + (ng * 2 + Mtt)) * 4 + rq];
                        unsigned b0 = (unsigned)((w >> fl) & 1ULL);
                        unsigned b1 = (unsigned)((w >> (32 + fl)) & 1ULL);
                        int t = Mtt * 8 + rq * 2;
                        mres |= (b0 << t) | (b1 << (t + 1));
                    }
                }
                mres &= 0x7FFFu;                // drop clamped t_loc = 15
                msk[((size_t)(i * BB + b) * 2 + h) * 64 + f] = mres;
            }
        }
    }
}

// ---------------------------------------------------------------------------
// Winners from half-masks: 2 coalesced u32 loads per lane. Verified formula:
// c=popcnt, first=min(30-c,29), fv=bit(first), total=c*(fv+30*any(fv)),
// first-occurrence argmax, -1 if total<=0.
// ---------------------------------------------------------------------------
__global__ __launch_bounds__(64) void win_msk(const unsigned* __restrict__ msk,
                                              float* __restrict__ out)
{
    const int blk = blockIdx.x;              // i*BB + b
    const int f   = threadIdx.x;
    unsigned m0 = msk[(size_t)blk * 128 + f];
    unsigned m1 = msk[(size_t)blk * 128 + 64 + f];
    unsigned mask = m0 | (m1 << 15);         // 30 t-bits
    int c     = __popc(mask);
    int first = TT - c; if (first > TT - 1) first = TT - 1;
    int fv    = (f < NF) ? (int)((mask >> first) & 1u) : 0;
    unsigned long long bal = __ballot(fv != 0);
    int v30 = (bal != 0ull) ? TT : 0;
    int tot = (f < NF) ? c * (fv + v30) : -1;
    int idx = f;
    for (int off = 32; off > 0; off >>= 1) {
        int ot = __shfl_xor(tot, off);
        int oi = __shfl_xor(idx, off);
        if (ot > tot || (ot == tot && oi < idx)) { tot = ot; idx = oi; }
    }
    if (f == 0) out[blk] = (float)((tot > 0) ? idx : -1);
}

// Fallback: winners straight from pots (if ws too small for mask buffer).
__global__ __launch_bounds__(64) void win_pots(float* __restrict__ out)
{
    const int blk = blockIdx.x;
    const int f   = threadIdx.x;
    const float* po = out + WIN_CNT + (size_t)blk * TT * NF * SECLEN;
    unsigned mask = 0u;
    if (f < NF) {
        for (int t = 0; t < TT; ++t) {
            const float4 v = *(const float4*)(po + ((size_t)t * NF + f) * SECLEN);
            float m = fmaxf(fmaxf(v.x, v.y), fmaxf(v.z, v.w));
            if (m >= THRESH) mask |= (1u << t);
        }
    }
    int c     = __popc(mask);
    int first = TT - c; if (first > TT - 1) first = TT - 1;
    int fv    = (f < NF) ? (int)((mask >> first) & 1u) : 0;
    unsigned long long bal = __ballot(fv != 0);
    int v30 = (bal != 0ull) ? TT : 0;
    int tot = (f < NF) ? c * (fv + v30) : -1;
    int idx = f;
    for (int off = 32; off > 0; off >>= 1) {
        int ot = __shfl_xor(tot, off);
        int oi = __shfl_xor(idx, off);
        if (ot > tot || (ot == tot && oi < idx)) { tot = ot; idx = oi; }
    }
    if (f == 0) out[blk] = (float)((tot > 0) ? idx : -1);
}

extern "C" void kernel_launch(void* const* d_in, const int* in_sizes, int n_in,
                              void* d_out, int out_size, void* d_ws, size_t ws_size,
                              hipStream_t stream)
{
    const float* x = (const float*)d_in[0];
    const float* W = (const float*)d_in[1];
    float* out = (float*)d_out;
    unsigned char* wsw = (unsigned char*)d_ws;
    unsigned* msk = (unsigned*)(wsw + WSW_BYTES);
    const bool use_msk = ws_size >= (size_t)(WSW_BYTES + MASK_BYTES);

    wconv_kernel<<<(NFRAG * 64 + 255) / 256, 256, 0, stream>>>(W, wsw);
    if (use_msk) {
        pots_mfma<true><<<BB * 2, 256, 0, stream>>>(x, wsw, out, msk);
        win_msk<<<NSEC * BB, 64, 0, stream>>>(msk, out);
    } else {
        pots_mfma<false><<<BB * 2, 256, 0, stream>>>(x, wsw, out, nullptr);
        win_pots<<<NSEC * BB, 64, 0, stream>>>(out);
    }
}